// Round 9
// baseline (760.748 us; speedup 1.0000x reference)
//
#include <hip/hip_runtime.h>

#define N_ 65536

typedef unsigned int  uint32;
typedef unsigned short ushort;
typedef float  f32x4 __attribute__((ext_vector_type(4)));
typedef short  s16x8 __attribute__((ext_vector_type(8)));
typedef uint32 u32x2 __attribute__((ext_vector_type(2)));
typedef uint32 u32x4 __attribute__((ext_vector_type(4)));

__device__ __forceinline__ uint32 f2bf(float f){
  union{float f; uint32 i;} v; v.f=f;
  return (v.i + 0x7fffu + ((v.i>>16)&1u)) >> 16;   // RNE
}
__device__ __forceinline__ float bfl(uint32 h){     // bf16 (low 16 bits) -> float
  union{uint32 i; float f;} v; v.i = h<<16; return v.f;
}
__device__ __forceinline__ uint32 pk2(float a, float b){
  return f2bf(a) | (f2bf(b)<<16);
}
__device__ __forceinline__ f32x4 mfma16(s16x8 a, s16x8 b, f32x4 c){
  return __builtin_amdgcn_mfma_f32_16x16x32_bf16(a,b,c,0,0,0);
}
__device__ __forceinline__ s16x8 mk8(uint32 a, uint32 b, uint32 c, uint32 d){
  union{u32x4 u; s16x8 s;} v; v.u = (u32x4){a,b,c,d}; return v.s;
}

// ---------------- prep: WlT[512][256], WfxT[256][256] (bf16, k-inner), blT[512] ----------------
__global__ __launch_bounds__(256) void prep_kernel(
    const float* __restrict__ Wfx, const float* __restrict__ Wx,
    const float* __restrict__ Wsl, const float* __restrict__ bsl,
    const float* __restrict__ bx,  const float* __restrict__ temp,
    ushort* __restrict__ WlT, ushort* __restrict__ WfxT, float* __restrict__ blT)
{
  const int blk = blockIdx.x, t = threadIdx.x;
  if (blk < 512){
    const int m = blk, h = m>>6, mp = m&63;
    const float tmp = fminf(fmaxf(temp[h],0.1f),5.0f);
    float s = 0.f;
    #pragma unroll
    for (int cc=0; cc<32; cc++) s += Wx[t*256 + h*32+cc]*Wsl[cc*64+mp];
    WlT[m*256+t] = (ushort)f2bf(s/tmp);
    if (t==0){
      float bs = bsl[mp];
      for (int cc=0; cc<32; cc++) bs += bx[h*32+cc]*Wsl[cc*64+mp];
      blT[m] = bs/tmp;
    }
  } else {
    const int c = blk-512;
    WfxT[c*256+t] = (ushort)f2bf(Wfx[t*256+c]);
  }
}

// ---------------- xbf: x (fp32) -> bf16, linear layout [131072 pts][256] ----------------
__global__ __launch_bounds__(256) void xbf_kernel(const float* __restrict__ x, ushort* __restrict__ xbf)
{
  const size_t i = ((size_t)blockIdx.x*256 + threadIdx.x)*8;
  const float4* xp = (const float4*)(x + i);
  const float4 a = xp[0], b = xp[1];
  u32x4 o; o.x = pk2(a.x,a.y); o.y = pk2(a.z,a.w); o.z = pk2(b.x,b.y); o.w = pk2(b.z,b.w);
  *(u32x4*)(xbf + i) = o;
}

// ---------------- k1b: fused proj + softmax + slice-token partials (NO swg store) ---------------
// Grid 512 x 512 thr; wave w = head w; 4 tiles of 64 pts. LDS 64KB (2 blocks/CU):
//   [0,32K): X tile [64 pt][512B], staged async (pre-swizzled source, linear LDS dest)
//   [32K,64K): per-wave swb at 32K + w*4K: [64 m][64 B], XOR ((row&7)<<3)
__global__ __launch_bounds__(512)
void k1b_kernel(
    const ushort* __restrict__ xbf,
    const ushort* __restrict__ WlT,
    const ushort* __restrict__ WfxT,
    const float* __restrict__ blT,
    const float* __restrict__ bfx,
    float* __restrict__ stp,        // [512 blk][8 h][32 c][64 m] f32
    float* __restrict__ normp)      // [512 blk][8 h][64 m]
{
  __shared__ __align__(16) char smem[65536];
  const int t = threadIdx.x;
  const int w = t>>6, l = t&63, rg = l>>4, c16 = l&15;
  const int blk = blockIdx.x;
  const int tile0 = ((blk&255)<<2) + ((blk>>8)<<10);

  char* swb = smem + 32768 + (w<<12);     // 4 KB per wave

  f32x4 pc[2][4];
  #pragma unroll
  for (int i=0;i<2;i++)
    #pragma unroll
    for (int j=0;j<4;j++) pc[i][j] = (f32x4){0.f,0.f,0.f,0.f};
  f32x4 nacc[4];
  #pragma unroll
  for (int i=0;i<4;i++) nacc[i] = (f32x4){0.f,0.f,0.f,0.f};
  float bfv[2];
  #pragma unroll
  for (int cf=0;cf<2;cf++) bfv[cf] = bfx[(w<<5)+(cf<<4)+c16];

  // async stage of a 64-pt tile (32 KB): 4 insts/thread; wave-uniform LDS base + lane*16.
  #define STAGE(TILE) { \
    const int gnS = (int)((TILE)<<6); \
    _Pragma("unroll") \
    for (int p=0;p<4;p++){ \
      const int row = (p<<4) + (t>>5); \
      const int z = (t&31)<<4; \
      const char* g = (const char*)xbf + (((size_t)(gnS+row))<<9) + (size_t)(z ^ ((row&7)<<4)); \
      uint32* ldsp = (uint32*)(smem + (p<<13) + ((t>>6)<<10)); \
      __builtin_amdgcn_global_load_lds((const uint32*)g, ldsp, 16, 0, 0); \
    } }

  STAGE(tile0);
  __syncthreads();

  for (int it=0; it<4; ++it){
    const long gn0 = (long)(tile0+it)<<6;
    (void)gn0;

    #pragma unroll
    for (int ch=0; ch<2; ch++){
      // ---- Phase A (logits^T): accA[mf][nfc], 32 pts per chunk ----
      f32x4 accA[4][2];
      #pragma unroll
      for (int mf=0;mf<4;mf++)
        #pragma unroll
        for (int nfc=0;nfc<2;nfc++) accA[mf][nfc] = (f32x4){0.f,0.f,0.f,0.f};
      #pragma unroll
      for (int kb=0;kb<8;kb++){
        s16x8 aW[4], xv[2];
        #pragma unroll
        for (int mf=0;mf<4;mf++)
          aW[mf] = *(const s16x8*)(WlT + (((w<<6)+(mf<<4)+c16)<<8) + (kb<<5)+(rg<<3));
        #pragma unroll
        for (int nfc=0;nfc<2;nfc++){
          const int row = (ch<<5) + (nfc<<4) + c16;
          xv[nfc] = *(const s16x8*)(smem + (row<<9) + (((kb<<6)+(rg<<4)) ^ ((row&7)<<4)));
        }
        #pragma unroll
        for (int mf=0;mf<4;mf++)
          #pragma unroll
          for (int nfc=0;nfc<2;nfc++)
            accA[mf][nfc] = mfma16(aW[mf], xv[nfc], accA[mf][nfc]);
      }
      // ---- softmax per 16-pt frag + swb pair-pack (no global store) ----
      #pragma unroll
      for (int nfc=0;nfc<2;nfc++){
        f32x4 v[4];
        float mx = -3.0e38f;
        #pragma unroll
        for (int mf=0;mf<4;mf++){
          const f32x4 bl4 = *(const f32x4*)(blT + (w<<6)+(mf<<4)+(rg<<2));
          v[mf] = accA[mf][nfc] + bl4;
          mx = fmaxf(mx, fmaxf(fmaxf(v[mf].x, v[mf].y), fmaxf(v[mf].z, v[mf].w)));
        }
        mx = fmaxf(mx, __shfl_xor(mx,16));
        mx = fmaxf(mx, __shfl_xor(mx,32));
        float s = 0.f;
        #pragma unroll
        for (int mf=0;mf<4;mf++){
          v[mf].x = __expf(v[mf].x-mx); v[mf].y = __expf(v[mf].y-mx);
          v[mf].z = __expf(v[mf].z-mx); v[mf].w = __expf(v[mf].w-mx);
          s += v[mf].x+v[mf].y+v[mf].z+v[mf].w;
        }
        s += __shfl_xor(s,16);
        s += __shfl_xor(s,32);
        const float inv = 1.0f/s;
        #pragma unroll
        for (int mf=0;mf<4;mf++){
          f32x4 sv = v[mf]*inv;
          nacc[mf] += sv;
          u32x2 p; p.x = pk2(sv.x, sv.y); p.y = pk2(sv.z, sv.w);
          // pair-pack transpose (regs=m) -> swb [m][32 pt of this chunk]
          const uint32 px = (uint32)__shfl_xor((int)p.x, 1);
          const uint32 py = (uint32)__shfl_xor((int)p.y, 1);
          const bool ev = ((c16&1)==0);
          const uint32 s0 = ev ? (uint32)p.x : py;
          const uint32 s1 = ev ? px : (uint32)p.y;
          const uint32 wA = (s0 & 0xffffu) | (s1<<16);
          const uint32 wB = (s0>>16) | (s1 & 0xffff0000u);
          const int rowA = (mf<<4) + (rg<<2) + (ev?0:2);
          const int cbyt = ((nfc<<4) | (c16 & ~1)) << 1;
          *(uint32*)(swb + ((rowA  )<<6) + (cbyt ^ (((rowA  )&7)<<3))) = wA;
          *(uint32*)(swb + ((rowA+1)<<6) + (cbyt ^ (((rowA+1)&7)<<3))) = wB;
        }
      }

      // ---- Phase B (fx): accB[pf][cf] for the chunk's 32 pts ----
      f32x4 accB[2][2];
      #pragma unroll
      for (int pf=0;pf<2;pf++)
        #pragma unroll
        for (int cf=0;cf<2;cf++) accB[pf][cf] = (f32x4){0.f,0.f,0.f,0.f};
      #pragma unroll
      for (int kb=0;kb<8;kb++){
        s16x8 bW[2], xv[2];
        #pragma unroll
        for (int cf=0;cf<2;cf++)
          bW[cf] = *(const s16x8*)(WfxT + (((w<<5)+(cf<<4)+c16)<<8) + (kb<<5)+(rg<<3));
        #pragma unroll
        for (int pf=0;pf<2;pf++){
          const int row = (ch<<5) + (pf<<4) + c16;
          xv[pf] = *(const s16x8*)(smem + (row<<9) + (((kb<<6)+(rg<<4)) ^ ((row&7)<<4)));
        }
        #pragma unroll
        for (int pf=0;pf<2;pf++)
          #pragma unroll
          for (int cf=0;cf<2;cf++)
            accB[pf][cf] = mfma16(xv[pf], bW[cf], accB[pf][cf]);
      }
      // ---- pack fx hi/lo as Phase-C A-frags (D/A layout identity) ----
      u32x4 afu[2][2];   // [cf][pf]
      #pragma unroll
      for (int cf=0;cf<2;cf++)
        #pragma unroll
        for (int pf=0;pf<2;pf++){
          const float v0 = accB[pf][cf].x+bfv[cf], v1 = accB[pf][cf].y+bfv[cf];
          const float v2 = accB[pf][cf].z+bfv[cf], v3 = accB[pf][cf].w+bfv[cf];
          const uint32 h0=f2bf(v0), h1=f2bf(v1), h2=f2bf(v2), h3=f2bf(v3);
          afu[cf][pf].x = h0|(h1<<16);
          afu[cf][pf].y = h2|(h3<<16);
          afu[cf][pf].z = f2bf(v0-bfl(h0)) | (f2bf(v1-bfl(h1))<<16);
          afu[cf][pf].w = f2bf(v2-bfl(h2)) | (f2bf(v3-bfl(h3))<<16);
        }
      asm volatile("s_waitcnt lgkmcnt(0)" ::: "memory");   // swb writes landed
      __builtin_amdgcn_sched_barrier(0);

      // ---- Phase C: pc[cf][mf] += fx(hi|lo) @ sw ----
      #pragma unroll
      for (int pf=0;pf<2;pf++)
        #pragma unroll
        for (int mf=0;mf<4;mf++){
          const int row = (mf<<4)+c16;
          const u32x2 q = *(const u32x2*)(swb + (row<<6) + ((((pf<<5)+(rg<<3)) ^ ((row&7)<<3))));
          const s16x8 bdup = mk8(q.x, q.y, q.x, q.y);
          pc[0][mf] = mfma16(mk8(afu[0][pf].x,afu[0][pf].y,afu[0][pf].z,afu[0][pf].w), bdup, pc[0][mf]);
          pc[1][mf] = mfma16(mk8(afu[1][pf].x,afu[1][pf].y,afu[1][pf].z,afu[1][pf].w), bdup, pc[1][mf]);
        }
      asm volatile("s_waitcnt lgkmcnt(0)" ::: "memory");   // C reads done before next chunk
      __builtin_amdgcn_sched_barrier(0);
    }
    __syncthreads();                               // all X reads done
    if (it<3){ STAGE(tile0+it+1); __syncthreads(); }
  }
  #undef STAGE

  // ---- epilogue: norm reduce + stores ----
  #pragma unroll
  for (int m=0;m<4;m++){
    #pragma unroll
    for (int d=1; d<16; d<<=1){
      nacc[m].x += __shfl_xor(nacc[m].x, d);
      nacc[m].y += __shfl_xor(nacc[m].y, d);
      nacc[m].z += __shfl_xor(nacc[m].z, d);
      nacc[m].w += __shfl_xor(nacc[m].w, d);
    }
  }
  if (c16==0){
    #pragma unroll
    for (int m=0;m<4;m++)
      *(f32x4*)(normp + (((blk<<3)+w)<<6) + (m<<4) + (rg<<2)) = nacc[m];
  }
  const long sb = ((long)((blk<<3)+w))<<11;   // stp[blk][w][32 c][64 m]
  #pragma unroll
  for (int cf=0;cf<2;cf++)
    #pragma unroll
    for (int mf=0;mf<4;mf++)
      #pragma unroll
      for (int r=0;r<4;r++){
        const int cc = (cf<<4)+(rg<<2)+r;
        stp[sb + (cc<<6) + (mf<<4) + c16] = pc[cf][mf][r];
      }
}

// ---------------- k2a: hierarchical partial reduce (512 blocks -> 16 slots of 8) ----------------
__global__ __launch_bounds__(256) void k2a_kernel(float* __restrict__ stp, float* __restrict__ normp)
{
  const int gid = blockIdx.x;           // 128 = 16 bh * 8 grp
  const int bh = gid>>3, grp = gid&7;
  const int b = bh>>3, h = bh&7;
  const int t = threadIdx.x;
  const int blk0 = (b<<8) + (grp<<5);
  f32x4 a0 = {0,0,0,0}, a1 = {0,0,0,0};
  for (int i=0;i<32;i++){
    const f32x4* p = (const f32x4*)(stp + ((((size_t)(blk0+i)<<3)+h)<<11) + ((size_t)t<<3));
    a0 += p[0]; a1 += p[1];
  }
  f32x4* q = (f32x4*)(stp + ((((size_t)blk0<<3)+h)<<11) + ((size_t)t<<3));
  q[0] = a0; q[1] = a1;
  if (t<8){
    f32x4 n0 = {0,0,0,0}, n1 = {0,0,0,0};
    for (int i=0;i<32;i++){
      const f32x4* p = (const f32x4*)(normp + (((blk0+i)<<3)+h)*64 + (t<<3));
      n0 += p[0]; n1 += p[1];
    }
    f32x4* qn = (f32x4*)(normp + ((blk0<<3)+h)*64 + (t<<3));
    qn[0] = n0; qn[1] = n1;
  }
}

// ---------------- k2b: final reduce + tiny attention + fold W_out -> OS2T hi/lo bf16 ------------
__global__ __launch_bounds__(256) void k2b_kernel(
    const float* __restrict__ stp, const float* __restrict__ normp,
    const float* __restrict__ Wq, const float* __restrict__ Wk, const float* __restrict__ Wv,
    const float* __restrict__ Wout, ushort* __restrict__ OS2Th, ushort* __restrict__ OS2Tl)
{
  __shared__ float nrmL[64];
  __shared__ float tok[2048];
  __shared__ float qL[2048], kL[2048], vL[2048];
  __shared__ float sc[4096];
  __shared__ float osL[2048];
  const int bh = blockIdx.x; const int b = bh>>3, h = bh&7;
  const int t = threadIdx.x;

  if (t<64){
    float s = 0.f;
    for (int g=0; g<8; g++) s += normp[((((b<<8)+(g<<5))<<3)+h)*64 + t];
    nrmL[t] = s;
  }
  __syncthreads();
  {
    f32x4 a0 = {0,0,0,0}, a1 = {0,0,0,0};
    for (int g=0; g<8; g++){
      const f32x4* p = (const f32x4*)(stp + ((((size_t)((b<<8)+(g<<5))<<3)+h)<<11) + ((size_t)t<<3));
      a0 += p[0]; a1 += p[1];
    }
    const int c = t>>3, m0 = (t&7)<<3;
    #pragma unroll
    for (int j=0;j<4;j++) tok[(m0+j)*32 + c]   = a0[j] / (nrmL[m0+j]   + 1e-5f);
    #pragma unroll
    for (int j=0;j<4;j++) tok[(m0+4+j)*32 + c] = a1[j] / (nrmL[m0+4+j] + 1e-5f);
  }
  __syncthreads();

  const int g = t>>2, q4 = t&3;
  float aq[8]={0,0,0,0,0,0,0,0}, ak2[8]={0,0,0,0,0,0,0,0}, av[8]={0,0,0,0,0,0,0,0};
  for (int kk=0; kk<32; kk++){
    const float tv = tok[(g<<5)+kk];
    const int wo = kk*32 + (q4<<3);
    #pragma unroll
    for (int j=0;j<8;j++){
      aq[j]  = fmaf(tv, Wq[wo+j], aq[j]);
      ak2[j] = fmaf(tv, Wk[wo+j], ak2[j]);
      av[j]  = fmaf(tv, Wv[wo+j], av[j]);
    }
  }
  #pragma unroll
  for (int j=0;j<8;j++){
    qL[(g<<5)+(q4<<3)+j]=aq[j];
    kL[(g<<5)+(q4<<3)+j]=ak2[j];
    vL[(g<<5)+(q4<<3)+j]=av[j];
  }
  __syncthreads();

  const float scale = 0.17677669529663689f;
  float svv[16]; float mx = -3.0e38f;
  for (int mm=0;mm<16;mm++){
    const int m = (q4<<4)+mm;
    float s2 = 0.f;
    #pragma unroll
    for (int c=0;c<32;c++) s2 = fmaf(qL[(g<<5)+c], kL[(m<<5)+c], s2);
    s2 *= scale;
    svv[mm] = s2; mx = fmaxf(mx, s2);
  }
  mx = fmaxf(mx, __shfl_xor(mx,1));
  mx = fmaxf(mx, __shfl_xor(mx,2));
  float ssum = 0.f;
  for (int mm=0;mm<16;mm++){ svv[mm] = __expf(svv[mm]-mx); ssum += svv[mm]; }
  ssum += __shfl_xor(ssum,1); ssum += __shfl_xor(ssum,2);
  const float isum = 1.0f/ssum;
  for (int mm=0;mm<16;mm++) sc[(g<<6) + (q4<<4) + mm] = svv[mm]*isum;
  __syncthreads();

  float os[8]={0,0,0,0,0,0,0,0};
  for (int m=0;m<64;m++){
    const float a = sc[(g<<6)+m];
    const int vo = (m<<5)+(q4<<3);
    #pragma unroll
    for (int j=0;j<8;j++) os[j] = fmaf(a, vL[vo+j], os[j]);
  }
  #pragma unroll
  for (int j=0;j<8;j++) osL[(g<<5)+(q4<<3)+j] = os[j];
  __syncthreads();

  // OS2T{h,l}[b][d][h*64+g] = sum_c os[g][c] * Wout[h*32+c][d]  (split bf16)
  const int d = t;
  float wcol[32];
  #pragma unroll
  for (int c=0;c<32;c++) wcol[c] = Wout[(h*32+c)*256 + d];
  uint32* orh = (uint32*)(OS2Th + ((size_t)(b*256+d))*512 + h*64);
  uint32* orl = (uint32*)(OS2Tl + ((size_t)(b*256+d))*512 + h*64);
  #pragma unroll 4
  for (int g2=0; g2<32; g2++){
    float s0=0.f, s1=0.f;
    #pragma unroll
    for (int c=0;c<32;c++){
      s0 = fmaf(osL[((g2*2  )<<5)+c], wcol[c], s0);
      s1 = fmaf(osL[((g2*2+1)<<5)+c], wcol[c], s1);
    }
    const uint32 h0 = f2bf(s0), h1 = f2bf(s1);
    orh[g2] = h0 | (h1<<16);
    orl[g2] = f2bf(s0 - bfl(h0)) | (f2bf(s1 - bfl(h1)) << 16);
  }
}

// ---------------- k3: recompute sw from xbf, scatter: out[pt][d] = sum_h,m sw*OS2 + b_out -------
// 2048 blocks x 256 thr (4 waves). Block = 64 pts. Wave w: softmax for pts w*16..+15,
// scatter for d-range w*64..+63 over all 64 pts. LDS: X 32KB + swT [64 pt][128B] 8KB.
__global__ __launch_bounds__(256)
void k3_kernel(
    const ushort* __restrict__ xbf,
    const ushort* __restrict__ WlT,
    const float* __restrict__ blT,
    const ushort* __restrict__ OS2Th,
    const ushort* __restrict__ OS2Tl,
    const float* __restrict__ bout,
    float* __restrict__ out)
{
  __shared__ __align__(16) char smem[40960];
  const int t = threadIdx.x;
  const int w = t>>6, l = t&63, rg = l>>4, c16 = l&15;
  const int blk = blockIdx.x;
  const long gn0 = (long)blk<<6;
  const int b = blk>>10;

  // stage X tile [64][512B] (swizzled source, linear LDS dest)
  #pragma unroll
  for (int p=0;p<8;p++){
    const int row = (p<<3) + (t>>5);
    const int z = (t&31)<<4;
    const char* g = (const char*)xbf + (((size_t)(gn0+row))<<9) + (size_t)(z ^ ((row&7)<<4));
    uint32* ldsp = (uint32*)(smem + (p<<12) + ((t>>6)<<10));
    __builtin_amdgcn_global_load_lds((const uint32*)g, ldsp, 16, 0, 0);
  }
  __syncthreads();

  f32x4 acc[4][4];     // [dfrag][ptfrag]
  #pragma unroll
  for (int i=0;i<4;i++)
    #pragma unroll
    for (int j=0;j<4;j++) acc[i][j] = (f32x4){0.f,0.f,0.f,0.f};

  const int xrow = (w<<4) + c16;

  for (int h=0; h<8; ++h){
    // ---- logits for this wave's 16 pts (bit-identical to k1b's accumulation) ----
    f32x4 accA[4];
    #pragma unroll
    for (int mf=0;mf<4;mf++) accA[mf] = (f32x4){0.f,0.f,0.f,0.f};
    #pragma unroll
    for (int kb=0;kb<8;kb++){
      s16x8 aW[4];
      #pragma unroll
      for (int mf=0;mf<4;mf++)
        aW[mf] = *(const s16x8*)(WlT + (((h<<6)+(mf<<4)+c16)<<8) + (kb<<5)+(rg<<3));
      const s16x8 xv = *(const s16x8*)(smem + (xrow<<9) + (((kb<<6)+(rg<<4)) ^ ((c16&7)<<4)));
      #pragma unroll
      for (int mf=0;mf<4;mf++)
        accA[mf] = mfma16(aW[mf], xv, accA[mf]);
    }
    // ---- softmax (same code) -> swT[pt][m] direct 8B stores ----
    {
      f32x4 v[4];
      float mx = -3.0e38f;
      #pragma unroll
      for (int mf=0;mf<4;mf++){
        const f32x4 bl4 = *(const f32x4*)(blT + (h<<6)+(mf<<4)+(rg<<2));
        v[mf] = accA[mf] + bl4;
        mx = fmaxf(mx, fmaxf(fmaxf(v[mf].x, v[mf].y), fmaxf(v[mf].z, v[mf].w)));
      }
      mx = fmaxf(mx, __shfl_xor(mx,16));
      mx = fmaxf(mx, __shfl_xor(mx,32));
      float s = 0.f;
      #pragma unroll
      for (int mf=0;mf<4;mf++){
        v[mf].x = __expf(v[mf].x-mx); v[mf].y = __expf(v[mf].y-mx);
        v[mf].z = __expf(v[mf].z-mx); v[mf].w = __expf(v[mf].w-mx);
        s += v[mf].x+v[mf].y+v[mf].z+v[mf].w;
      }
      s += __shfl_xor(s,16);
      s += __shfl_xor(s,32);
      const float inv = 1.0f/s;
      #pragma unroll
      for (int mf=0;mf<4;mf++){
        f32x4 sv = v[mf]*inv;
        u32x2 p; p.x = pk2(sv.x, sv.y); p.y = pk2(sv.z, sv.w);
        // swT row = xrow (pt 0..63), byte offset m*2 = mf*32+rg*8, XOR ((c16&7)<<4)
        *(u32x2*)(smem + 32768 + (xrow<<7) + (((mf<<5)+(rg<<3)) ^ ((c16&7)<<4))) = p;
      }
    }
    __syncthreads();   // swT complete for all 64 pts

    // ---- scatter: acc[df][pf] += OS2T(hi|lo)[d][m] * swT[pt][m] ----
    #pragma unroll
    for (int kb2=0;kb2<2;kb2++){
      s16x8 bfr[4];
      #pragma unroll
      for (int pf=0;pf<4;pf++){
        const int prow = (pf<<4)+c16;
        bfr[pf] = *(const s16x8*)(smem + 32768 + (prow<<7) + (((kb2<<6)+(rg<<4)) ^ ((c16&7)<<4)));
      }
      #pragma unroll
      for (int df=0;df<4;df++){
        const long ro = (((long)(b<<8) + (w<<6)+(df<<4)+c16)<<9) + (h<<6) + (kb2<<5)+(rg<<3);
        const s16x8 aOh = *(const s16x8*)(OS2Th + ro);
        const s16x8 aOl = *(const s16x8*)(OS2Tl + ro);
        #pragma unroll
        for (int pf=0;pf<4;pf++)
          acc[df][pf] = mfma16(aOh, bfr[pf], acc[df][pf]);
        #pragma unroll
        for (int pf=0;pf<4;pf++)
          acc[df][pf] = mfma16(aOl, bfr[pf], acc[df][pf]);
      }
    }
    __syncthreads();   // scatter reads done before next head's swT overwrite
  }

  // ---- epilogue: coalesced f32x4 stores + bias ----
  #pragma unroll
  for (int df=0;df<4;df++){
    const int d0 = (w<<6)+(df<<4)+(rg<<2);
    const f32x4 bo = *(const f32x4*)(bout + d0);
    #pragma unroll
    for (int pf=0;pf<4;pf++){
      float* o = out + ((gn0 + (pf<<4)+c16)<<8) + d0;
      *(f32x4*)o = acc[df][pf] + bo;
    }
  }
}

extern "C" void kernel_launch(void* const* d_in, const int* in_sizes, int n_in,
                              void* d_out, int out_size, void* d_ws, size_t ws_size,
                              hipStream_t stream)
{
  const float* x     = (const float*)d_in[0];
  const float* Wfx   = (const float*)d_in[1];
  const float* bfx   = (const float*)d_in[2];
  const float* Wx    = (const float*)d_in[3];
  const float* bx    = (const float*)d_in[4];
  const float* Wsl   = (const float*)d_in[5];
  const float* bsl   = (const float*)d_in[6];
  const float* temp  = (const float*)d_in[7];
  const float* Wq    = (const float*)d_in[8];
  const float* Wk    = (const float*)d_in[9];
  const float* Wv    = (const float*)d_in[10];
  const float* Wout  = (const float*)d_in[11];
  const float* bout  = (const float*)d_in[12];
  float* out = (float*)d_out;

  char* ws = (char*)d_ws;
  // ws layout (bytes), total 103,155,712 (< 152,963,072 proven available):
  ushort* WlT   = (ushort*)(ws);                   // 262144
  ushort* WfxT  = (ushort*)(ws + 262144);          // 131072
  float*  blT   = (float*) (ws + 393216);          // 2048
  ushort* xbf   = (ushort*)(ws + 395264);          // 67108864  [131072][256] bf16
  float*  stp   = (float*) (ws + 67504128);        // 33554432  [512][8][32][64]
  float*  normp = (float*) (ws + 101058560);       // 1048576   [512][8][64]
  ushort* OS2Th = (ushort*)(ws + 102107136);       // 524288
  ushort* OS2Tl = (ushort*)(ws + 102631424);       // 524288

  prep_kernel<<<dim3(768), dim3(256), 0, stream>>>(Wfx, Wx, Wsl, bsl, bx, temp, WlT, WfxT, blT);
  xbf_kernel<<<dim3(16384), dim3(256), 0, stream>>>(x, xbf);
  k1b_kernel<<<dim3(512), dim3(512), 0, stream>>>(xbf, WlT, WfxT, blT, bfx, stp, normp);
  k2a_kernel<<<dim3(128), dim3(256), 0, stream>>>(stp, normp);
  k2b_kernel<<<dim3(16), dim3(256), 0, stream>>>(stp, normp, Wq, Wk, Wv, Wout, OS2Th, OS2Tl);
  k3_kernel<<<dim3(2048), dim3(256), 0, stream>>>(xbf, WlT, blT, OS2Th, OS2Tl, bout, out);
}

// Round 10
// 463.349 us; speedup vs baseline: 1.6418x; 1.6418x over previous
//
#include <hip/hip_runtime.h>

#define N_ 65536

typedef unsigned int  uint32;
typedef unsigned short ushort;
typedef float  f32x4 __attribute__((ext_vector_type(4)));
typedef short  s16x8 __attribute__((ext_vector_type(8)));
typedef uint32 u32x2 __attribute__((ext_vector_type(2)));
typedef uint32 u32x4 __attribute__((ext_vector_type(4)));

__device__ __forceinline__ uint32 f2bf(float f){
  union{float f; uint32 i;} v; v.f=f;
  return (v.i + 0x7fffu + ((v.i>>16)&1u)) >> 16;   // RNE
}
__device__ __forceinline__ float bfl(uint32 h){     // bf16 (low 16 bits) -> float
  union{uint32 i; float f;} v; v.i = h<<16; return v.f;
}
__device__ __forceinline__ uint32 pk2(float a, float b){
  return f2bf(a) | (f2bf(b)<<16);
}
__device__ __forceinline__ f32x4 mfma16(s16x8 a, s16x8 b, f32x4 c){
  return __builtin_amdgcn_mfma_f32_16x16x32_bf16(a,b,c,0,0,0);
}
__device__ __forceinline__ s16x8 mk8(uint32 a, uint32 b, uint32 c, uint32 d){
  union{u32x4 u; s16x8 s;} v; v.u = (u32x4){a,b,c,d}; return v.s;
}

// ---------------- prep: WlT[512][256], WfxT[256][256] (bf16, k-inner), blT[512] ----------------
__global__ __launch_bounds__(256) void prep_kernel(
    const float* __restrict__ Wfx, const float* __restrict__ Wx,
    const float* __restrict__ Wsl, const float* __restrict__ bsl,
    const float* __restrict__ bx,  const float* __restrict__ temp,
    ushort* __restrict__ WlT, ushort* __restrict__ WfxT, float* __restrict__ blT)
{
  const int blk = blockIdx.x, t = threadIdx.x;
  if (blk < 512){
    const int m = blk, h = m>>6, mp = m&63;
    const float tmp = fminf(fmaxf(temp[h],0.1f),5.0f);
    float s = 0.f;
    #pragma unroll
    for (int cc=0; cc<32; cc++) s += Wx[t*256 + h*32+cc]*Wsl[cc*64+mp];
    WlT[m*256+t] = (ushort)f2bf(s/tmp);
    if (t==0){
      float bs = bsl[mp];
      for (int cc=0; cc<32; cc++) bs += bx[h*32+cc]*Wsl[cc*64+mp];
      blT[m] = bs/tmp;
    }
  } else {
    const int c = blk-512;
    WfxT[c*256+t] = (ushort)f2bf(Wfx[t*256+c]);
  }
}

// ---------------- k1a: fused proj + softmax + slice-token partials (round-6 structure) ----------
// 64-pt tiles, 8 per block. LDS map (128 KiB):
//   [0,32K):   X tile [64 pt][512B] swizzled; after S3 per-wave fxh overlay at w*4K
//   [32K,96K): per-wave swL at 32K+w*8K: [64 m][128B] swizzled (wave-private)
//   [96K,128K): per-wave fxl at 96K+w*4K: [32 c][128B] swizzled (wave-private)
// ONLY change vs the measured-267us round-6 kernel: swg store -> coalesced packet layout
//   swg2 ushort idx = (((pb*8+h)*4+mf)*4+rg)*64 + c16*4 + j   (pb = flat_pt/16)
__global__ __launch_bounds__(512, 2)
void k1a_kernel(
    const float* __restrict__ x,
    const ushort* __restrict__ WlT,
    const ushort* __restrict__ WfxT,
    const float* __restrict__ blT,
    const float* __restrict__ bfx,
    ushort* __restrict__ swg2,      // [8192 pb][8 h][4 mf][4 rg][16 c16][4 j] bf16 packets
    float* __restrict__ stp,        // [256 blk][8 h][32 c][64 m] f32
    float* __restrict__ normp)      // [256 blk][8 h][64 m]
{
  __shared__ __align__(16) char smem[131072];
  const int t = threadIdx.x;
  const int w = t>>6, l = t&63, rg = l>>4, c16 = l&15;
  const int blk = blockIdx.x;
  const int tile0 = ((blk&127)<<3) + ((blk>>7)<<10);

  char* fxh = smem + (w<<12);             // 4 KB per wave (X overlay, post-S3)
  char* swb = smem + 32768 + (w<<13);     // 8 KB per wave
  char* fxl = smem + 98304 + (w<<12);     // 4 KB per wave (dedicated)

  f32x4 pc[2][4];      // Phase C accumulators: [c-frag][m-frag]
  #pragma unroll
  for (int i=0;i<2;i++)
    #pragma unroll
    for (int j=0;j<4;j++) pc[i][j] = (f32x4){0.f,0.f,0.f,0.f};
  f32x4 nacc[4];
  #pragma unroll
  for (int i=0;i<4;i++) nacc[i] = (f32x4){0.f,0.f,0.f,0.f};

  f32x4 blv[4];
  #pragma unroll
  for (int m=0;m<4;m++) blv[m] = *(const f32x4*)(blT + (w<<6)+(m<<4)+(rg<<2));
  float bfv[2];
  #pragma unroll
  for (int c=0;c<2;c++) bfv[c] = bfx[(w<<5)+(c<<4)+c16];

  for (int it=0; it<8; ++it) {
    const int tile = tile0 + it;
    const long gn0 = (long)tile<<6;

    __syncthreads();   // S1: prev tile's Phase-C reads (incl. fxh overlay) done
    // ---- stage X tile [64][256] -> bf16 LDS, XOR-swizzled ----
    {
      const float4* xs = (const float4*)(x + (gn0<<8));
      #pragma unroll
      for (int p=0;p<8;p++){
        const int f = t + (p<<9);
        const int row = f>>6, q = f&63;
        const float4 v = xs[f];
        u32x2 uu; uu.x = pk2(v.x, v.y); uu.y = pk2(v.z, v.w);
        *(u32x2*)(smem + (row<<9) + ((q<<3) ^ ((row&7)<<4))) = uu;
      }
    }
    __syncthreads();   // S2: X ready

    // ---- Phase A (logits^T = WlT @ X^T), one 16-pt fragment at a time ----
    #pragma unroll
    for (int nf=0; nf<4; nf++){
      f32x4 accA[4];
      #pragma unroll
      for (int m=0;m<4;m++) accA[m] = (f32x4){0.f,0.f,0.f,0.f};
      #pragma unroll
      for (int kb=0;kb<8;kb++){
        s16x8 aW[4], bX;
        #pragma unroll
        for (int m=0;m<4;m++)
          aW[m] = *(const s16x8*)(WlT + (((w<<6)+(m<<4)+c16)<<8) + (kb<<5)+(rg<<3));
        {
          const int row = (nf<<4) | c16;
          bX = *(const s16x8*)(smem + (row<<9) + (((kb<<6)+(rg<<4)) ^ ((row&7)<<4)));
        }
        #pragma unroll
        for (int m=0;m<4;m++)
          accA[m] = mfma16(aW[m], bX, accA[m]);
      }
      // softmax over m (4 m-frags in-reg x 4 rg-groups cross-lane), per pt column
      {
        f32x4 v[4];
        float mx = -3.0e38f;
        #pragma unroll
        for (int m=0;m<4;m++){
          v[m] = accA[m] + blv[m];
          mx = fmaxf(mx, fmaxf(fmaxf(v[m].x, v[m].y), fmaxf(v[m].z, v[m].w)));
        }
        mx = fmaxf(mx, __shfl_xor(mx,16));
        mx = fmaxf(mx, __shfl_xor(mx,32));
        float s = 0.f;
        #pragma unroll
        for (int m=0;m<4;m++){
          v[m].x = __expf(v[m].x-mx); v[m].y = __expf(v[m].y-mx);
          v[m].z = __expf(v[m].z-mx); v[m].w = __expf(v[m].w-mx);
          s += v[m].x+v[m].y+v[m].z+v[m].w;
        }
        s += __shfl_xor(s,16);
        s += __shfl_xor(s,32);
        const float inv = 1.0f/s;
        const int pb = (int)(gn0>>4) + nf;
        #pragma unroll
        for (int m=0;m<4;m++){
          f32x4 sv = v[m]*inv;
          nacc[m] += sv;
          u32x2 p; p.x = pk2(sv.x, sv.y); p.y = pk2(sv.z, sv.w);
          // coalesced packet store (64 lanes = 512B contiguous)
          *(u32x2*)(swg2 + ((((((size_t)pb<<3)+w)<<2)+m)<<8) + (rg<<6) + (c16<<2)) = p;
          // pair-pack transpose (regs=m) -> swL [m][pt], immediately (no persistence)
          const uint32 px = (uint32)__shfl_xor((int)p.x, 1);
          const uint32 py = (uint32)__shfl_xor((int)p.y, 1);
          const bool ev = ((c16&1)==0);
          const uint32 s0 = ev ? (uint32)p.x : py;
          const uint32 s1 = ev ? px : (uint32)p.y;
          const uint32 wA = (s0 & 0xffffu) | (s1<<16);
          const uint32 wB = (s0>>16) | (s1 & 0xffff0000u);
          const int rowA = (m<<4) + (rg<<2) + (ev?0:2);
          const int cbyt = ((nf<<4) + (c16 & ~1)) << 1;
          *(uint32*)(swb + ((rowA  )<<7) + (cbyt ^ (((rowA  )&7)<<4))) = wA;
          *(uint32*)(swb + ((rowA+1)<<7) + (cbyt ^ (((rowA+1)&7)<<4))) = wB;
        }
      }
    }

    // ---- Phase B (fx = X @ Wfx): hi kept in regs (16), lo staged to LDS directly ----
    u32x2 qkh[2][4];
    {
      f32x4 accB[4][2];
      #pragma unroll
      for (int r=0;r<4;r++)
        #pragma unroll
        for (int c=0;c<2;c++) accB[r][c] = (f32x4){0.f,0.f,0.f,0.f};
      #pragma unroll
      for (int kb=0;kb<8;kb++){
        s16x8 bW[2], aX[4];
        #pragma unroll
        for (int c=0;c<2;c++)
          bW[c] = *(const s16x8*)(WfxT + (((w<<5)+(c<<4)+c16)<<8) + (kb<<5)+(rg<<3));
        #pragma unroll
        for (int r=0;r<4;r++){
          const int row = (r<<4) | c16;
          aX[r] = *(const s16x8*)(smem + (row<<9) + (((kb<<6)+(rg<<4)) ^ ((row&7)<<4)));
        }
        #pragma unroll
        for (int r=0;r<4;r++)
          #pragma unroll
          for (int c=0;c<2;c++)
            accB[r][c] = mfma16(aX[r], bW[c], accB[r][c]);
      }
      #pragma unroll
      for (int r=0;r<4;r++)
        #pragma unroll
        for (int c=0;c<2;c++){
          const float v0 = accB[r][c].x+bfv[c], v1 = accB[r][c].y+bfv[c];
          const float v2 = accB[r][c].z+bfv[c], v3 = accB[r][c].w+bfv[c];
          const uint32 h0=f2bf(v0), h1=f2bf(v1), h2=f2bf(v2), h3=f2bf(v3);
          u32x2 ph; ph.x = h0|(h1<<16); ph.y = h2|(h3<<16);
          qkh[c][r] = ph;
          u32x2 pl;
          pl.x = f2bf(v0-bfl(h0)) | (f2bf(v1-bfl(h1))<<16);
          pl.y = f2bf(v2-bfl(h2)) | (f2bf(v3-bfl(h3))<<16);
          const int row = (c<<4) + c16;
          const int cby = ((r<<5) + (rg<<3)) ^ ((row&7)<<4);
          *(u32x2*)(fxl + (row<<7) + cby) = pl;
        }
    }
    __syncthreads();   // S3: all waves done reading X -> fxh overlay allowed

    // ---- stage fx-hi into overlay ----
    #pragma unroll
    for (int cf=0; cf<2; cf++)
      #pragma unroll
      for (int r=0; r<4; r++){
        const int row = (cf<<4) + c16;
        const int cby = ((r<<5) + (rg<<3)) ^ ((row&7)<<4);
        *(u32x2*)(fxh + (row<<7) + cby) = qkh[cf][r];
      }
    asm volatile("s_waitcnt lgkmcnt(0)" ::: "memory");
    __builtin_amdgcn_sched_barrier(0);

    // ---- Phase C: pc[c][m] += fx^T-frag @ sw-frag ----
    #pragma unroll
    for (int kb2=0; kb2<2; kb2++){
      const int pby = (kb2<<6) + (rg<<4);
      s16x8 afh[2], afl[2], bfr[4];
      #pragma unroll
      for (int cf=0; cf<2; cf++){
        const int row = (cf<<4)+c16;
        const int o = pby ^ ((row&7)<<4);
        afh[cf] = *(const s16x8*)(fxh + (row<<7) + o);
        afl[cf] = *(const s16x8*)(fxl + (row<<7) + o);
      }
      #pragma unroll
      for (int mf=0; mf<4; mf++){
        const int row = (mf<<4)+c16;
        bfr[mf] = *(const s16x8*)(swb + (row<<7) + (pby ^ ((row&7)<<4)));
      }
      #pragma unroll
      for (int cf=0; cf<2; cf++)
        #pragma unroll
        for (int mf=0; mf<4; mf++){
          pc[cf][mf] = mfma16(afh[cf], bfr[mf], pc[cf][mf]);
          pc[cf][mf] = mfma16(afl[cf], bfr[mf], pc[cf][mf]);
        }
    }
  } // tiles

  // ---- epilogue: norm reduce + stores ----
  #pragma unroll
  for (int m=0;m<4;m++){
    #pragma unroll
    for (int d=1; d<16; d<<=1){
      nacc[m].x += __shfl_xor(nacc[m].x, d);
      nacc[m].y += __shfl_xor(nacc[m].y, d);
      nacc[m].z += __shfl_xor(nacc[m].z, d);
      nacc[m].w += __shfl_xor(nacc[m].w, d);
    }
  }
  if (c16==0){
    #pragma unroll
    for (int m=0;m<4;m++)
      *(f32x4*)(normp + (((blk<<3)+w)<<6) + (m<<4) + (rg<<2)) = nacc[m];
  }
  const long sb = ((long)((blk<<3)+w))<<11;   // stp[blk][w][32 c][64 m]
  #pragma unroll
  for (int cf=0;cf<2;cf++)
    #pragma unroll
    for (int mf=0;mf<4;mf++)
      #pragma unroll
      for (int r=0;r<4;r++){
        const int cc = (cf<<4)+(rg<<2)+r;
        stp[sb + (cc<<6) + (mf<<4) + c16] = pc[cf][mf][r];
      }
}

// ---------------- k2a: hierarchical partial reduce (round-6 verbatim) ----------------
__global__ __launch_bounds__(256) void k2a_kernel(float* __restrict__ stp, float* __restrict__ normp)
{
  const int gid = blockIdx.x;           // 128 = 16 bh * 8 grp
  const int bh = gid>>3, grp = gid&7;
  const int b = bh>>3, h = bh&7;
  const int t = threadIdx.x;
  const int blk0 = (b<<7) + (grp<<4);
  f32x4 a0 = {0,0,0,0}, a1 = {0,0,0,0};
  for (int i=0;i<16;i++){
    const f32x4* p = (const f32x4*)(stp + ((((size_t)(blk0+i)<<3)+h)<<11) + ((size_t)t<<3));
    a0 += p[0]; a1 += p[1];
  }
  f32x4* q = (f32x4*)(stp + ((((size_t)blk0<<3)+h)<<11) + ((size_t)t<<3));
  q[0] = a0; q[1] = a1;
  if (t<8){
    f32x4 n0 = {0,0,0,0}, n1 = {0,0,0,0};
    for (int i=0;i<16;i++){
      const f32x4* p = (const f32x4*)(normp + (((blk0+i)<<3)+h)*64 + (t<<3));
      n0 += p[0]; n1 += p[1];
    }
    f32x4* qn = (f32x4*)(normp + ((blk0<<3)+h)*64 + (t<<3));
    qn[0] = n0; qn[1] = n1;
  }
}

// ---------------- k2b: final reduce + tiny attention + fold W_out (round-6 verbatim) ------------
__global__ __launch_bounds__(256) void k2b_kernel(
    const float* __restrict__ stp, const float* __restrict__ normp,
    const float* __restrict__ Wq, const float* __restrict__ Wk, const float* __restrict__ Wv,
    const float* __restrict__ Wout, ushort* __restrict__ OS2Th, ushort* __restrict__ OS2Tl)
{
  __shared__ float nrmL[64];
  __shared__ float tok[2048];
  __shared__ float qL[2048], kL[2048], vL[2048];
  __shared__ float sc[4096];
  __shared__ float osL[2048];
  const int bh = blockIdx.x; const int b = bh>>3, h = bh&7;
  const int t = threadIdx.x;

  if (t<64){
    float s = 0.f;
    for (int g=0; g<8; g++) s += normp[((((b<<7)+(g<<4))<<3)+h)*64 + t];
    nrmL[t] = s;
  }
  __syncthreads();
  {
    f32x4 a0 = {0,0,0,0}, a1 = {0,0,0,0};
    for (int g=0; g<8; g++){
      const f32x4* p = (const f32x4*)(stp + ((((size_t)((b<<7)+(g<<4))<<3)+h)<<11) + ((size_t)t<<3));
      a0 += p[0]; a1 += p[1];
    }
    const int c = t>>3, m0 = (t&7)<<3;
    #pragma unroll
    for (int j=0;j<4;j++) tok[(m0+j)*32 + c]   = a0[j] / (nrmL[m0+j]   + 1e-5f);
    #pragma unroll
    for (int j=0;j<4;j++) tok[(m0+4+j)*32 + c] = a1[j] / (nrmL[m0+4+j] + 1e-5f);
  }
  __syncthreads();

  const int g = t>>2, q4 = t&3;
  float aq[8]={0,0,0,0,0,0,0,0}, ak2[8]={0,0,0,0,0,0,0,0}, av[8]={0,0,0,0,0,0,0,0};
  for (int kk=0; kk<32; kk++){
    const float tv = tok[(g<<5)+kk];
    const int wo = kk*32 + (q4<<3);
    #pragma unroll
    for (int j=0;j<8;j++){
      aq[j]  = fmaf(tv, Wq[wo+j], aq[j]);
      ak2[j] = fmaf(tv, Wk[wo+j], ak2[j]);
      av[j]  = fmaf(tv, Wv[wo+j], av[j]);
    }
  }
  #pragma unroll
  for (int j=0;j<8;j++){
    qL[(g<<5)+(q4<<3)+j]=aq[j];
    kL[(g<<5)+(q4<<3)+j]=ak2[j];
    vL[(g<<5)+(q4<<3)+j]=av[j];
  }
  __syncthreads();

  const float scale = 0.17677669529663689f;
  float svv[16]; float mx = -3.0e38f;
  for (int mm=0;mm<16;mm++){
    const int m = (q4<<4)+mm;
    float s2 = 0.f;
    #pragma unroll
    for (int c=0;c<32;c++) s2 = fmaf(qL[(g<<5)+c], kL[(m<<5)+c], s2);
    s2 *= scale;
    svv[mm] = s2; mx = fmaxf(mx, s2);
  }
  mx = fmaxf(mx, __shfl_xor(mx,1));
  mx = fmaxf(mx, __shfl_xor(mx,2));
  float ssum = 0.f;
  for (int mm=0;mm<16;mm++){ svv[mm] = __expf(svv[mm]-mx); ssum += svv[mm]; }
  ssum += __shfl_xor(ssum,1); ssum += __shfl_xor(ssum,2);
  const float isum = 1.0f/ssum;
  for (int mm=0;mm<16;mm++) sc[(g<<6) + (q4<<4) + mm] = svv[mm]*isum;
  __syncthreads();

  float os[8]={0,0,0,0,0,0,0,0};
  for (int m=0;m<64;m++){
    const float a = sc[(g<<6)+m];
    const int vo = (m<<5)+(q4<<3);
    #pragma unroll
    for (int j=0;j<8;j++) os[j] = fmaf(a, vL[vo+j], os[j]);
  }
  #pragma unroll
  for (int j=0;j<8;j++) osL[(g<<5)+(q4<<3)+j] = os[j];
  __syncthreads();

  // OS2T{h,l}[b][d][h*64+g] = sum_c os[g][c] * Wout[h*32+c][d]  (split bf16)
  const int d = t;
  float wcol[32];
  #pragma unroll
  for (int c=0;c<32;c++) wcol[c] = Wout[(h*32+c)*256 + d];
  uint32* orh = (uint32*)(OS2Th + ((size_t)(b*256+d))*512 + h*64);
  uint32* orl = (uint32*)(OS2Tl + ((size_t)(b*256+d))*512 + h*64);
  #pragma unroll 4
  for (int g2=0; g2<32; g2++){
    float s0=0.f, s1=0.f;
    #pragma unroll
    for (int c=0;c<32;c++){
      s0 = fmaf(osL[((g2*2  )<<5)+c], wcol[c], s0);
      s1 = fmaf(osL[((g2*2+1)<<5)+c], wcol[c], s1);
    }
    const uint32 h0 = f2bf(s0), h1 = f2bf(s1);
    orh[g2] = h0 | (h1<<16);
    orl[g2] = f2bf(s0 - bfl(h0)) | (f2bf(s1 - bfl(h1)) << 16);
  }
}

// ---------------- k3: out = sw @ (OS2Th+OS2Tl)^T + b_out (round-8 verbatim: packet reads) -------
__global__ __launch_bounds__(256) void k3_kernel(
    const ushort* __restrict__ swg2,
    const ushort* __restrict__ OS2Th,
    const ushort* __restrict__ OS2Tl,
    const float* __restrict__ bout,
    float* __restrict__ out)
{
  const int t = threadIdx.x, w = t>>6, l = t&63, rg = l>>4, c16 = l&15;
  const int blk = blockIdx.x;
  const long gn0 = (long)blk<<6;          // 64 pts per block
  const int b = blk>>10;
  f32x4 acc[4][4];
  #pragma unroll
  for (int r=0;r<4;r++)
    #pragma unroll
    for (int c=0;c<4;c++) acc[r][c] = (f32x4){0.f,0.f,0.f,0.f};
  const long obb = (((long)(b<<8) + (w<<6))<<9);
  for (int kb=0;kb<16;kb++){
    const int h3 = kb>>1;
    const int mb = ((kb&1)<<1) + (rg>>1);
    const int pkt = (rg&1)<<1;
    s16x8 aS[4];
    #pragma unroll
    for (int r=0;r<4;r++){
      const long pb = (gn0>>4) + r;
      const ushort* bp = swg2 + ((((pb<<3)+h3)<<2) + mb)*256 + (c16<<2);
      const u32x2 lo = *(const u32x2*)(bp + (pkt<<6));
      const u32x2 hi = *(const u32x2*)(bp + ((pkt+1)<<6));
      aS[r] = mk8(lo.x, lo.y, hi.x, hi.y);
    }
    #pragma unroll
    for (int c=0;c<4;c++){
      const long ro = obb + ((long)((c<<4)+c16)<<9) + (kb<<5)+(rg<<3);
      const s16x8 bhv = *(const s16x8*)(OS2Th + ro);
      const s16x8 blv = *(const s16x8*)(OS2Tl + ro);
      #pragma unroll
      for (int r=0;r<4;r++)
        acc[r][c] = mfma16(aS[r], bhv, acc[r][c]);
      #pragma unroll
      for (int r=0;r<4;r++)
        acc[r][c] = mfma16(aS[r], blv, acc[r][c]);
    }
  }
  float bo[4];
  #pragma unroll
  for (int c=0;c<4;c++) bo[c] = bout[(w<<6)+(c<<4)+c16];
  #pragma unroll
  for (int r=0;r<4;r++)
    #pragma unroll
    for (int c=0;c<4;c++)
      #pragma unroll
      for (int rr=0;rr<4;rr++)
        out[((gn0 + (r<<4)+(rg<<2)+rr)<<8) + (w<<6)+(c<<4)+c16] = acc[r][c][rr] + bo[c];
}

extern "C" void kernel_launch(void* const* d_in, const int* in_sizes, int n_in,
                              void* d_out, int out_size, void* d_ws, size_t ws_size,
                              hipStream_t stream)
{
  const float* x     = (const float*)d_in[0];
  const float* Wfx   = (const float*)d_in[1];
  const float* bfx   = (const float*)d_in[2];
  const float* Wx    = (const float*)d_in[3];
  const float* bx    = (const float*)d_in[4];
  const float* Wsl   = (const float*)d_in[5];
  const float* bsl   = (const float*)d_in[6];
  const float* temp  = (const float*)d_in[7];
  const float* Wq    = (const float*)d_in[8];
  const float* Wk    = (const float*)d_in[9];
  const float* Wv    = (const float*)d_in[10];
  const float* Wout  = (const float*)d_in[11];
  const float* bout  = (const float*)d_in[12];
  float* out = (float*)d_out;

  char* ws = (char*)d_ws;
  // ws layout (bytes), total 152,963,072 (round-5/6 proven size):
  ushort* WlT   = (ushort*)(ws);                   // 262144
  ushort* WfxT  = (ushort*)(ws + 262144);          // 131072
  float*  blT   = (float*) (ws + 393216);          // 2048
  ushort* swg2  = (ushort*)(ws + 395264);          // 134217728
  float*  stp   = (float*) (ws + 134612992);       // 16777216
  float*  normp = (float*) (ws + 151390208);       // 524288
  ushort* OS2Th = (ushort*)(ws + 151914496);       // 524288
  ushort* OS2Tl = (ushort*)(ws + 152438784);       // 524288

  prep_kernel<<<dim3(768), dim3(256), 0, stream>>>(Wfx, Wx, Wsl, bsl, bx, temp, WlT, WfxT, blT);
  k1a_kernel<<<dim3(256), dim3(512), 0, stream>>>(x, WlT, WfxT, blT, bfx, swg2, stp, normp);
  k2a_kernel<<<dim3(128), dim3(256), 0, stream>>>(stp, normp);
  k2b_kernel<<<dim3(16), dim3(256), 0, stream>>>(stp, normp, Wq, Wk, Wv, Wout, OS2Th, OS2Tl);
  k3_kernel<<<dim3(2048), dim3(256), 0, stream>>>(swg2, OS2Th, OS2Tl, bout, out);
}